// Round 1
// baseline (1266.758 us; speedup 1.0000x reference)
//
#include <hip/hip_runtime.h>
#include <cstddef>

#define B_    128
#define NV_   100
#define NQ_   14
#define NA_   10
#define HDIM  512
#define RANK_ 32
#define HD_   16
#define G_    2
// output cols per b-row: NQ*NA*G = 280; rows per b: NV=100; K of final GEMM = RANK*HD = 512

// C[M,N] = relu(A[M,K] @ W[N,K]^T + bias[N]); requires M%128==0, N%128==0, K%16==0
__global__ __launch_bounds__(256) void gemm_relu128(
    const float* __restrict__ A, const float* __restrict__ W,
    const float* __restrict__ bias, float* __restrict__ C,
    int M, int N, int K)
{
  __shared__ float As[16][132];
  __shared__ float Ws[16][132];
  const int bn = blockIdx.x * 128;
  const int bm = blockIdx.y * 128;
  const int t  = threadIdx.x;
  const int tx = t & 15;   // col group
  const int ty = t >> 4;   // row group
  const int lm = t >> 2;          // 0..63
  const int lk = (t & 3) << 2;    // 0,4,8,12

  float acc[8][8];
  #pragma unroll
  for (int i = 0; i < 8; ++i)
    #pragma unroll
    for (int j = 0; j < 8; ++j) acc[i][j] = 0.f;

  for (int k0 = 0; k0 < K; k0 += 16) {
    float4 a0 = *(const float4*)(A + (size_t)(bm + lm)      * K + k0 + lk);
    float4 a1 = *(const float4*)(A + (size_t)(bm + lm + 64) * K + k0 + lk);
    float4 w0 = *(const float4*)(W + (size_t)(bn + lm)      * K + k0 + lk);
    float4 w1 = *(const float4*)(W + (size_t)(bn + lm + 64) * K + k0 + lk);
    As[lk+0][lm]    = a0.x; As[lk+1][lm]    = a0.y; As[lk+2][lm]    = a0.z; As[lk+3][lm]    = a0.w;
    As[lk+0][lm+64] = a1.x; As[lk+1][lm+64] = a1.y; As[lk+2][lm+64] = a1.z; As[lk+3][lm+64] = a1.w;
    Ws[lk+0][lm]    = w0.x; Ws[lk+1][lm]    = w0.y; Ws[lk+2][lm]    = w0.z; Ws[lk+3][lm]    = w0.w;
    Ws[lk+0][lm+64] = w1.x; Ws[lk+1][lm+64] = w1.y; Ws[lk+2][lm+64] = w1.z; Ws[lk+3][lm+64] = w1.w;
    __syncthreads();
    #pragma unroll
    for (int kk = 0; kk < 16; ++kk) {
      float4 af0 = *(const float4*)&As[kk][ty * 4];
      float4 af1 = *(const float4*)&As[kk][64 + ty * 4];
      float4 wf0 = *(const float4*)&Ws[kk][tx * 4];
      float4 wf1 = *(const float4*)&Ws[kk][64 + tx * 4];
      float af[8] = {af0.x, af0.y, af0.z, af0.w, af1.x, af1.y, af1.z, af1.w};
      float wf[8] = {wf0.x, wf0.y, wf0.z, wf0.w, wf1.x, wf1.y, wf1.z, wf1.w};
      #pragma unroll
      for (int i = 0; i < 8; ++i)
        #pragma unroll
        for (int j = 0; j < 8; ++j)
          acc[i][j] += af[i] * wf[j];
    }
    __syncthreads();
  }

  #pragma unroll
  for (int ih = 0; ih < 2; ++ih) {
    #pragma unroll
    for (int i = 0; i < 4; ++i) {
      const int row = bm + ih * 64 + ty * 4 + i;
      #pragma unroll
      for (int jh = 0; jh < 2; ++jh) {
        const int col = bn + jh * 64 + tx * 4;
        float4 o;
        o.x = fmaxf(acc[ih*4+i][jh*4+0] + bias[col+0], 0.f);
        o.y = fmaxf(acc[ih*4+i][jh*4+1] + bias[col+1], 0.f);
        o.z = fmaxf(acc[ih*4+i][jh*4+2] + bias[col+2], 0.f);
        o.w = fmaxf(acc[ih*4+i][jh*4+3] + bias[col+3], 0.f);
        *(float4*)(C + (size_t)row * N + col) = o;
      }
    }
  }
}

// Tsum[i,j,k,g] = sum_r T[r,i,j,k,g];  8192 outputs
__global__ void tsum_kernel(const float* __restrict__ T, float* __restrict__ Tsum)
{
  const int idx = blockIdx.x * 256 + threadIdx.x;  // < 8192
  float s = 0.f;
  #pragma unroll
  for (int r = 0; r < RANK_; ++r) s += T[r * 8192 + idx];
  Tsum[idx] = s;
}

// Per (b,n): U[q,i,k,g] = sum_j Tsum[i,j,k,g]*q_[b,q,n*16+j];
//            Wmat[b, n*16+i, (q*10+a)*2+g] = sum_k U[q,i,k,g]*a_[b,a,n*16+k]
__global__ __launch_bounds__(256) void build_w_kernel(
    const float* __restrict__ q_, const float* __restrict__ a_,
    const float* __restrict__ Tsum, float* __restrict__ Wmat)
{
  const int n = blockIdx.x;   // 0..31
  const int b = blockIdx.y;   // 0..127
  const int t = threadIdx.x;
  __shared__ float Ts[8192];            // [i][j][k][g]
  __shared__ float U[NQ_ * 16 * 16 * G_]; // [q][i][k][g] = 7168
  __shared__ float qn[NQ_][16];
  __shared__ float an[NA_][16];

  #pragma unroll
  for (int s = 0; s < 32; ++s) Ts[s * 256 + t] = Tsum[s * 256 + t];
  if (t < NQ_ * 16) {
    int q = t >> 4, j = t & 15;
    qn[q][j] = q_[((size_t)(b * NQ_ + q)) * HDIM + n * 16 + j];
  }
  if (t < NA_ * 16) {
    int a = t >> 4, k = t & 15;
    an[a][k] = a_[((size_t)(b * NA_ + a)) * HDIM + n * 16 + k];
  }
  __syncthreads();

  // U: 7168 = 28*256 exactly
  #pragma unroll
  for (int s = 0; s < 28; ++s) {
    int e = s * 256 + t;
    int g = e & 1;
    int k = (e >> 1) & 15;
    int i = (e >> 5) & 15;
    int q = e >> 9;
    float acc = 0.f;
    #pragma unroll
    for (int j = 0; j < 16; ++j)
      acc += Ts[((i * 16 + j) * 16 + k) * 2 + g] * qn[q][j];
    U[e] = acc;  // layout q*512 + i*32 + k*2 + g
  }
  __syncthreads();

  // W: 16*280 = 4480 outputs
  #pragma unroll
  for (int s = 0; s < 18; ++s) {
    int e = s * 256 + t;
    if (e < 16 * 280) {
      int c = e % 280;
      int i = e / 280;
      int g = c & 1;
      int a = (c >> 1) % 10;
      int q = c / 20;
      float acc = 0.f;
      #pragma unroll
      for (int k = 0; k < 16; ++k)
        acc += U[q * 512 + i * 32 + k * 2 + g] * an[a][k];
      Wmat[((size_t)b * 512 + (n * 16 + i)) * 280 + c] = acc;
    }
  }
}

// Per b: out[b,100,280] = v_[b,100,512] @ Wmat[b,512,280]; block = 16 rows x 280 cols
__global__ __launch_bounds__(256) void final_contract(
    const float* __restrict__ Vr, const float* __restrict__ Wmat,
    float* __restrict__ out)
{
  __shared__ float vs[16][33];
  __shared__ float wsh[32][320];  // padded: cols 280..319 uninit, never stored
  const int b    = blockIdx.y;
  const int row0 = blockIdx.x * 16;
  const int t  = threadIdx.x;
  const int tx = t & 63;   // col base
  const int ty = t >> 6;   // row group (wave index)

  float acc[4][5];
  #pragma unroll
  for (int i = 0; i < 4; ++i)
    #pragma unroll
    for (int s = 0; s < 5; ++s) acc[i][s] = 0.f;

  const float* Vb = Vr   + (size_t)b * NV_ * HDIM;
  const float* Wb = Wmat + (size_t)b * 512 * 280;

  for (int k0 = 0; k0 < 512; k0 += 32) {
    if (t < 128) {
      int r  = t >> 3;
      int kk = (t & 7) << 2;
      int rload = row0 + r; if (rload > NV_ - 1) rload = NV_ - 1;
      float4 vv = *(const float4*)(Vb + (size_t)rload * HDIM + k0 + kk);
      vs[r][kk+0] = vv.x; vs[r][kk+1] = vv.y; vs[r][kk+2] = vv.z; vs[r][kk+3] = vv.w;
    }
    #pragma unroll
    for (int s4 = 0; s4 < 9; ++s4) {
      int e4 = s4 * 256 + t;
      if (e4 < 2240) {                 // 32 rows x 70 float4
        int kk = e4 / 70;
        int c4 = (e4 - kk * 70) << 2;
        float4 wv = *(const float4*)(Wb + (size_t)(k0 + kk) * 280 + c4);
        wsh[kk][c4+0] = wv.x; wsh[kk][c4+1] = wv.y; wsh[kk][c4+2] = wv.z; wsh[kk][c4+3] = wv.w;
      }
    }
    __syncthreads();
    #pragma unroll
    for (int kk = 0; kk < 32; ++kk) {
      float av[4];
      #pragma unroll
      for (int i = 0; i < 4; ++i) av[i] = vs[ty * 4 + i][kk];
      #pragma unroll
      for (int s = 0; s < 5; ++s) {
        float wv = wsh[kk][tx + 64 * s];   // s=4,tx>=24 reads padded lane: unused
        #pragma unroll
        for (int i = 0; i < 4; ++i)
          acc[i][s] += av[i] * wv;
      }
    }
    __syncthreads();
  }

  #pragma unroll
  for (int i = 0; i < 4; ++i) {
    const int row = row0 + ty * 4 + i;
    if (row < NV_) {
      #pragma unroll
      for (int s = 0; s < 5; ++s) {
        const int c = tx + 64 * s;
        if (c < 280)
          out[(size_t)b * (NV_ * 280) + (size_t)row * 280 + c] = acc[i][s];
      }
    }
  }
}

extern "C" void kernel_launch(void* const* d_in, const int* in_sizes, int n_in,
                              void* d_out, int out_size, void* d_ws, size_t ws_size,
                              hipStream_t stream)
{
  const float* v   = (const float*)d_in[0];
  const float* q   = (const float*)d_in[1];
  const float* a   = (const float*)d_in[2];
  const float* Wv  = (const float*)d_in[3];
  const float* bv  = (const float*)d_in[4];
  const float* Wq  = (const float*)d_in[5];
  const float* bq  = (const float*)d_in[6];
  const float* Wa  = (const float*)d_in[7];
  const float* ba  = (const float*)d_in[8];
  const float* Wvr = (const float*)d_in[9];
  const float* bvr = (const float*)d_in[10];
  const float* Wqr = (const float*)d_in[11];
  const float* bqr = (const float*)d_in[12];
  const float* War = (const float*)d_in[13];
  const float* bar = (const float*)d_in[14];
  const float* T   = (const float*)d_in[15];
  float* ws = (float*)d_ws;

  // workspace layout (floats)
  float* Wmat = ws;                        // 128*512*280     = 18,350,080
  float* v_r  = ws + 18350080;             // 12800*512       =  6,553,600
  float* q_r  = v_r + 6553600;             // 1792*512        =    917,504
  float* a_r  = q_r + 917504;              // 1280*512        =    655,360
  float* Tsum = a_r + 655360;              //                 =      8,192
  // temporaries overlaid on Wmat region (dead before build_w writes Wmat):
  float* vt   = ws;                        // 6,553,600
  float* qt   = ws + 6553600;              //   917,504
  float* at   = qt + 917504;               //   655,360

  // modality projections (relu GEMMs)
  gemm_relu128<<<dim3(4, 100), 256, 0, stream>>>(v, Wv, bv, vt, 12800, 512, 2048);
  gemm_relu128<<<dim3(4, 14),  256, 0, stream>>>(q, Wq, bq, qt,  1792, 512, 1024);
  gemm_relu128<<<dim3(4, 10),  256, 0, stream>>>(a, Wa, ba, at,  1280, 512, 1024);
  // rank-wise projections: Wvr [32,16,512] flattened to [512,512]
  gemm_relu128<<<dim3(4, 100), 256, 0, stream>>>(vt, Wvr, bvr, v_r, 12800, 512, 512);
  gemm_relu128<<<dim3(4, 14),  256, 0, stream>>>(qt, Wqr, bqr, q_r,  1792, 512, 512);
  gemm_relu128<<<dim3(4, 10),  256, 0, stream>>>(at, War, bar, a_r,  1280, 512, 512);
  // rank-sum of the Tucker core
  tsum_kernel<<<32, 256, 0, stream>>>(T, Tsum);
  // per-(b,n) contraction of q_ and a_ into the core
  build_w_kernel<<<dim3(32, 128), 256, 0, stream>>>(q_r, a_r, Tsum, Wmat);
  // final batched GEMM into f_emb
  final_contract<<<dim3(7, 128), 256, 0, stream>>>(v_r, Wmat, (float*)d_out);
}

// Round 2
// 596.528 us; speedup vs baseline: 2.1236x; 2.1236x over previous
//
#include <hip/hip_runtime.h>
#include <cstddef>
#include <cstdint>

#define B_    128
#define NV_   100
#define NQ_   14
#define NA_   10
#define HDIM  512
#define RANK_ 32
#define HD_   16
#define G_    2

typedef __bf16 bf16x8 __attribute__((ext_vector_type(8)));
typedef float  f32x4  __attribute__((ext_vector_type(4)));
union Frag { uint4 u; bf16x8 v; };

__device__ __forceinline__ unsigned short f2bf(float f) {
  unsigned int u = __float_as_uint(f);
  u = (u + 0x7FFFu + ((u >> 16) & 1u)) >> 16;
  return (unsigned short)u;
}

// ---------------------------------------------------------------------------
// fused fp32 -> bf16 conversion of all 9 bf16-consumed inputs.
// All segment sizes are multiples of 2048; dst is one contiguous ushort region.
__global__ __launch_bounds__(256) void cvt_kernel(
    const float* __restrict__ s0, const float* __restrict__ s1,
    const float* __restrict__ s2, const float* __restrict__ s3,
    const float* __restrict__ s4, const float* __restrict__ s5,
    const float* __restrict__ s6, const float* __restrict__ s7,
    const float* __restrict__ s8, unsigned short* __restrict__ dst)
{
  const int pref[9] = {12800, 13696, 14336, 14848, 15104, 15360, 15488, 15616, 15744};
  const float* srcs[9] = {s0, s1, s2, s3, s4, s5, s6, s7, s8};
  const int blk = blockIdx.x;
  int seg = 0;
  #pragma unroll
  for (int i = 0; i < 9; ++i) if (blk >= pref[i]) seg = i + 1;
  const int base_chunk = seg ? pref[seg - 1] : 0;
  const size_t loc = (size_t)(blk - base_chunk) * 2048 + threadIdx.x * 8;
  const float* s = srcs[seg] + loc;
  float4 f0 = *(const float4*)s;
  float4 f1 = *(const float4*)(s + 4);
  ushort4 o0, o1;
  o0.x = f2bf(f0.x); o0.y = f2bf(f0.y); o0.z = f2bf(f0.z); o0.w = f2bf(f0.w);
  o1.x = f2bf(f1.x); o1.y = f2bf(f1.y); o1.z = f2bf(f1.z); o1.w = f2bf(f1.w);
  unsigned short* d = dst + (size_t)blk * 2048 + threadIdx.x * 8;
  *(ushort4*)d = o0;
  *(ushort4*)(d + 4) = o1;
}

// ---------------------------------------------------------------------------
// C[M,N] = relu(A[M,K] @ W[N,K]^T + bias[N]); A,W bf16; M%128==0, N%128==0, K%32==0
// m97 structure: 128x128 block tile, BK=32, 4 waves of 64x64, global_load_lds(16B)
template <bool OUT_BF16>
__global__ __launch_bounds__(256) void gemm_mfma(
    const unsigned short* __restrict__ A, const unsigned short* __restrict__ W,
    const float* __restrict__ bias, void* __restrict__ Cout,
    int M, int N, int K)
{
  __shared__ __align__(16) unsigned short As[4096];  // [128][32]
  __shared__ __align__(16) unsigned short Bs[4096];  // [128][32]
  const int bn = blockIdx.x * 128;
  const int bm = blockIdx.y * 128;
  const int t  = threadIdx.x;
  const int w  = t >> 6;       // wave 0..3
  const int l  = t & 63;       // lane
  const int wm = (w >> 1) * 64;
  const int wn = (w & 1) * 64;
  const int rr = l >> 2;          // staging row within 16-row chunk
  const int ko = (l & 3) * 8;     // staging k-offset (bf16 elems)

  f32x4 acc[4][4];
  #pragma unroll
  for (int i = 0; i < 4; ++i)
    #pragma unroll
    for (int j = 0; j < 4; ++j) acc[i][j] = f32x4{0.f, 0.f, 0.f, 0.f};

  for (int k0 = 0; k0 < K; k0 += 32) {
    #pragma unroll
    for (int c2 = 0; c2 < 2; ++c2) {
      const int c = w * 2 + c2;  // chunk 0..7 (16 rows each)
      const unsigned short* gpA = A + (size_t)(bm + c * 16 + rr) * K + k0 + ko;
      const unsigned short* gpB = W + (size_t)(bn + c * 16 + rr) * K + k0 + ko;
      __builtin_amdgcn_global_load_lds(
          (const __attribute__((address_space(1))) void*)gpA,
          (__attribute__((address_space(3))) void*)&As[c * 512], 16, 0, 0);
      __builtin_amdgcn_global_load_lds(
          (const __attribute__((address_space(1))) void*)gpB,
          (__attribute__((address_space(3))) void*)&Bs[c * 512], 16, 0, 0);
    }
    __syncthreads();

    Frag fa[4], fb[4];
    #pragma unroll
    for (int i = 0; i < 4; ++i)
      fa[i].u = *(const uint4*)&As[(wm + 16 * i + (l & 15)) * 32 + (l >> 4) * 8];
    #pragma unroll
    for (int j = 0; j < 4; ++j)
      fb[j].u = *(const uint4*)&Bs[(wn + 16 * j + (l & 15)) * 32 + (l >> 4) * 8];
    #pragma unroll
    for (int i = 0; i < 4; ++i)
      #pragma unroll
      for (int j = 0; j < 4; ++j)
        acc[i][j] = __builtin_amdgcn_mfma_f32_16x16x32_bf16(fa[i].v, fb[j].v, acc[i][j], 0, 0, 0);
    __syncthreads();
  }

  const int q4 = (l >> 4) * 4;
  const int cl = l & 15;
  #pragma unroll
  for (int i = 0; i < 4; ++i) {
    #pragma unroll
    for (int j = 0; j < 4; ++j) {
      const int col = bn + wn + 16 * j + cl;
      const float bs = bias[col];
      #pragma unroll
      for (int r = 0; r < 4; ++r) {
        const int row = bm + wm + 16 * i + q4 + r;
        float o = acc[i][j][r] + bs;
        o = fmaxf(o, 0.f);
        if (OUT_BF16)
          ((unsigned short*)Cout)[(size_t)row * N + col] = f2bf(o);
        else
          ((float*)Cout)[(size_t)row * N + col] = o;
      }
    }
  }
}

// ---------------------------------------------------------------------------
// Tsum[i,j,k,g] = sum_r T[r,i,j,k,g]
__global__ void tsum_kernel(const float* __restrict__ T, float* __restrict__ Tsum)
{
  const int idx = blockIdx.x * 256 + threadIdx.x;  // < 8192
  float s = 0.f;
  #pragma unroll
  for (int r = 0; r < RANK_; ++r) s += T[r * 8192 + idx];
  Tsum[idx] = s;
}

// ---------------------------------------------------------------------------
// Per (b,n): U[q,i,k,g] = sum_j Tsum[i,j,k,g]*q_[b,q,n*16+j];
//            Wmat[b, n*16+i, (q*10+a)*2+g] = sum_k U[q,i,k,g]*a_[b,a,n*16+k]
__global__ __launch_bounds__(256) void build_w_kernel(
    const float* __restrict__ q_, const float* __restrict__ a_,
    const float* __restrict__ Tsum, float* __restrict__ Wmat)
{
  const int n = blockIdx.x;   // 0..31
  const int b = blockIdx.y;   // 0..127
  const int t = threadIdx.x;
  __shared__ float Ts[8192];
  __shared__ float U[NQ_ * 16 * 16 * G_];  // 7168
  __shared__ float qn[NQ_][16];
  __shared__ float an[NA_][16];

  #pragma unroll
  for (int s = 0; s < 32; ++s) Ts[s * 256 + t] = Tsum[s * 256 + t];
  if (t < NQ_ * 16) {
    int q = t >> 4, j = t & 15;
    qn[q][j] = q_[((size_t)(b * NQ_ + q)) * HDIM + n * 16 + j];
  }
  if (t < NA_ * 16) {
    int a = t >> 4, k = t & 15;
    an[a][k] = a_[((size_t)(b * NA_ + a)) * HDIM + n * 16 + k];
  }
  __syncthreads();

  #pragma unroll
  for (int s = 0; s < 28; ++s) {
    int e = s * 256 + t;
    int g = e & 1;
    int k = (e >> 1) & 15;
    int i = (e >> 5) & 15;
    int q = e >> 9;
    float acc = 0.f;
    #pragma unroll
    for (int j = 0; j < 16; ++j)
      acc += Ts[((i * 16 + j) * 16 + k) * 2 + g] * qn[q][j];
    U[e] = acc;
  }
  __syncthreads();

  #pragma unroll
  for (int s = 0; s < 18; ++s) {
    int e = s * 256 + t;
    if (e < 16 * 280) {
      int c = e % 280;
      int i = e / 280;
      int g = c & 1;
      int a = (c >> 1) % 10;
      int q = c / 20;
      float acc = 0.f;
      #pragma unroll
      for (int k = 0; k < 16; ++k)
        acc += U[q * 512 + i * 32 + k * 2 + g] * an[a][k];
      Wmat[((size_t)b * 512 + (n * 16 + i)) * 280 + c] = acc;
    }
  }
}

// ---------------------------------------------------------------------------
// Per b: out[b,100,280] = v_[b,100,512] @ Wmat[b,512,280]
__global__ __launch_bounds__(256) void final_contract(
    const float* __restrict__ Vr, const float* __restrict__ Wmat,
    float* __restrict__ out)
{
  __shared__ float vs[16][33];
  __shared__ float wsh[32][320];
  const int b    = blockIdx.y;
  const int row0 = blockIdx.x * 16;
  const int t  = threadIdx.x;
  const int tx = t & 63;
  const int ty = t >> 6;

  float acc[4][5];
  #pragma unroll
  for (int i = 0; i < 4; ++i)
    #pragma unroll
    for (int s = 0; s < 5; ++s) acc[i][s] = 0.f;

  const float* Vb = Vr   + (size_t)b * NV_ * HDIM;
  const float* Wb = Wmat + (size_t)b * 512 * 280;

  for (int k0 = 0; k0 < 512; k0 += 32) {
    if (t < 128) {
      int r  = t >> 3;
      int kk = (t & 7) << 2;
      int rload = row0 + r; if (rload > NV_ - 1) rload = NV_ - 1;
      float4 vv = *(const float4*)(Vb + (size_t)rload * HDIM + k0 + kk);
      vs[r][kk+0] = vv.x; vs[r][kk+1] = vv.y; vs[r][kk+2] = vv.z; vs[r][kk+3] = vv.w;
    }
    #pragma unroll
    for (int s4 = 0; s4 < 9; ++s4) {
      int e4 = s4 * 256 + t;
      if (e4 < 2240) {
        int kk = e4 / 70;
        int c4 = (e4 - kk * 70) << 2;
        float4 wv = *(const float4*)(Wb + (size_t)(k0 + kk) * 280 + c4);
        wsh[kk][c4+0] = wv.x; wsh[kk][c4+1] = wv.y; wsh[kk][c4+2] = wv.z; wsh[kk][c4+3] = wv.w;
      }
    }
    __syncthreads();
    #pragma unroll
    for (int kk = 0; kk < 32; ++kk) {
      float av[4];
      #pragma unroll
      for (int i = 0; i < 4; ++i) av[i] = vs[ty * 4 + i][kk];
      #pragma unroll
      for (int s = 0; s < 5; ++s) {
        float wv = wsh[kk][tx + 64 * s];
        #pragma unroll
        for (int i = 0; i < 4; ++i)
          acc[i][s] += av[i] * wv;
      }
    }
    __syncthreads();
  }

  #pragma unroll
  for (int i = 0; i < 4; ++i) {
    const int row = row0 + ty * 4 + i;
    if (row < NV_) {
      #pragma unroll
      for (int s = 0; s < 5; ++s) {
        const int c = tx + 64 * s;
        if (c < 280)
          out[(size_t)b * (NV_ * 280) + (size_t)row * 280 + c] = acc[i][s];
      }
    }
  }
}

// ---------------------------------------------------------------------------
extern "C" void kernel_launch(void* const* d_in, const int* in_sizes, int n_in,
                              void* d_out, int out_size, void* d_ws, size_t ws_size,
                              hipStream_t stream)
{
  const float* v   = (const float*)d_in[0];
  const float* q   = (const float*)d_in[1];
  const float* a   = (const float*)d_in[2];
  const float* Wv  = (const float*)d_in[3];
  const float* bv  = (const float*)d_in[4];
  const float* Wq  = (const float*)d_in[5];
  const float* bq  = (const float*)d_in[6];
  const float* Wa  = (const float*)d_in[7];
  const float* ba  = (const float*)d_in[8];
  const float* Wvr = (const float*)d_in[9];
  const float* bvr = (const float*)d_in[10];
  const float* Wqr = (const float*)d_in[11];
  const float* bqr = (const float*)d_in[12];
  const float* War = (const float*)d_in[13];
  const float* bar = (const float*)d_in[14];
  const float* T   = (const float*)d_in[15];

  float* ws = (float*)d_ws;
  unsigned short* wsu = (unsigned short*)d_ws;

  // fp32 workspace (floats)
  float* Wmat = ws;                       // 18,350,080 (overlaid by bf16 inputs early)
  float* v_r  = ws + 18350080;            //  6,553,600
  float* q_r  = ws + 24903680;            //    917,504
  float* a_r  = ws + 25821184;            //    655,360
  float* Tsum = ws + 26476544;            //      8,192
  // bf16 intermediates (ushort), after fp32 region
  unsigned short* vtb = (unsigned short*)(ws + 26484736);  // 6,553,600 ush
  unsigned short* qtb = vtb + 6553600;                     //   917,504 ush
  unsigned short* atb = qtb + 917504;                      //   655,360 ush

  // bf16 input region overlaid on Wmat (consumed before build_w writes Wmat)
  unsigned short* vb   = wsu;              // 26,214,400
  unsigned short* qb   = wsu + 26214400;   //  1,835,008
  unsigned short* ab   = wsu + 28049408;   //  1,310,720
  unsigned short* Wvb  = wsu + 29360128;   //  1,048,576
  unsigned short* Wqb  = wsu + 30408704;   //    524,288
  unsigned short* Wab  = wsu + 30932992;   //    524,288
  unsigned short* Wvrb = wsu + 31457280;   //    262,144
  unsigned short* Wqrb = wsu + 31719424;   //    262,144
  unsigned short* Warb = wsu + 31981568;   //    262,144

  cvt_kernel<<<15744, 256, 0, stream>>>(v, q, a, Wv, Wq, Wa, Wvr, Wqr, War, wsu);

  // layer 1: modality projections (bf16 out)
  gemm_mfma<true><<<dim3(4, 100), 256, 0, stream>>>(vb, Wvb, bv, vtb, 12800, 512, 2048);
  gemm_mfma<true><<<dim3(4, 14),  256, 0, stream>>>(qb, Wqb, bq, qtb,  1792, 512, 1024);
  gemm_mfma<true><<<dim3(4, 10),  256, 0, stream>>>(ab, Wab, ba, atb,  1280, 512, 1024);
  // layer 2: rank-wise projections (fp32 out)
  gemm_mfma<false><<<dim3(4, 100), 256, 0, stream>>>(vtb, Wvrb, bvr, v_r, 12800, 512, 512);
  gemm_mfma<false><<<dim3(4, 14),  256, 0, stream>>>(qtb, Wqrb, bqr, q_r,  1792, 512, 512);
  gemm_mfma<false><<<dim3(4, 10),  256, 0, stream>>>(atb, Warb, bar, a_r,  1280, 512, 512);

  tsum_kernel<<<32, 256, 0, stream>>>(T, Tsum);
  build_w_kernel<<<dim3(32, 128), 256, 0, stream>>>(q_r, a_r, Tsum, Wmat);
  final_contract<<<dim3(7, 128), 256, 0, stream>>>(v_r, Wmat, (float*)d_out);
}

// Round 4
// 409.685 us; speedup vs baseline: 3.0920x; 1.4561x over previous
//
#include <hip/hip_runtime.h>
#include <cstddef>
#include <cstdint>

#define B_    128
#define NV_   100
#define NQ_   14
#define NA_   10
#define HDIM  512
#define RANK_ 32
#define HD_   16
#define G_    2

typedef __bf16 bf16x8 __attribute__((ext_vector_type(8)));
typedef float  f32x4  __attribute__((ext_vector_type(4)));
union Frag { uint4 u; bf16x8 v; };

__device__ __forceinline__ unsigned short f2bf(float f) {
  unsigned int u = __float_as_uint(f);
  u = (u + 0x7FFFu + ((u >> 16) & 1u)) >> 16;
  return (unsigned short)u;
}

// ---------------------------------------------------------------------------
// fused fp32 -> bf16 conversion of all 9 bf16-consumed inputs.
__global__ __launch_bounds__(256) void cvt_kernel(
    const float* __restrict__ s0, const float* __restrict__ s1,
    const float* __restrict__ s2, const float* __restrict__ s3,
    const float* __restrict__ s4, const float* __restrict__ s5,
    const float* __restrict__ s6, const float* __restrict__ s7,
    const float* __restrict__ s8, unsigned short* __restrict__ dst)
{
  const int pref[9] = {12800, 13696, 14336, 14848, 15104, 15360, 15488, 15616, 15744};
  const float* srcs[9] = {s0, s1, s2, s3, s4, s5, s6, s7, s8};
  const int blk = blockIdx.x;
  int seg = 0;
  #pragma unroll
  for (int i = 0; i < 9; ++i) if (blk >= pref[i]) seg = i + 1;
  const int base_chunk = seg ? pref[seg - 1] : 0;
  const size_t loc = (size_t)(blk - base_chunk) * 2048 + threadIdx.x * 8;
  const float* s = srcs[seg] + loc;
  float4 f0 = *(const float4*)s;
  float4 f1 = *(const float4*)(s + 4);
  ushort4 o0, o1;
  o0.x = f2bf(f0.x); o0.y = f2bf(f0.y); o0.z = f2bf(f0.z); o0.w = f2bf(f0.w);
  o1.x = f2bf(f1.x); o1.y = f2bf(f1.y); o1.z = f2bf(f1.z); o1.w = f2bf(f1.w);
  unsigned short* d = dst + (size_t)blk * 2048 + threadIdx.x * 8;
  *(ushort4*)d = o0;
  *(ushort4*)(d + 4) = o1;
}

// ---------------------------------------------------------------------------
// C[M,N] = relu(A[M,K] @ W[N,K]^T + bias[N]); A,W bf16
template <bool OUT_BF16>
__global__ __launch_bounds__(256) void gemm_mfma(
    const unsigned short* __restrict__ A, const unsigned short* __restrict__ W,
    const float* __restrict__ bias, void* __restrict__ Cout,
    int M, int N, int K)
{
  __shared__ __align__(16) unsigned short As[4096];  // [128][32]
  __shared__ __align__(16) unsigned short Bs[4096];  // [128][32]
  const int bn = blockIdx.x * 128;
  const int bm = blockIdx.y * 128;
  const int t  = threadIdx.x;
  const int w  = t >> 6;
  const int l  = t & 63;
  const int wm = (w >> 1) * 64;
  const int wn = (w & 1) * 64;
  const int rr = l >> 2;
  const int ko = (l & 3) * 8;

  f32x4 acc[4][4];
  #pragma unroll
  for (int i = 0; i < 4; ++i)
    #pragma unroll
    for (int j = 0; j < 4; ++j) acc[i][j] = f32x4{0.f, 0.f, 0.f, 0.f};

  for (int k0 = 0; k0 < K; k0 += 32) {
    #pragma unroll
    for (int c2 = 0; c2 < 2; ++c2) {
      const int c = w * 2 + c2;
      const unsigned short* gpA = A + (size_t)(bm + c * 16 + rr) * K + k0 + ko;
      const unsigned short* gpB = W + (size_t)(bn + c * 16 + rr) * K + k0 + ko;
      __builtin_amdgcn_global_load_lds(
          (const __attribute__((address_space(1))) void*)gpA,
          (__attribute__((address_space(3))) void*)&As[c * 512], 16, 0, 0);
      __builtin_amdgcn_global_load_lds(
          (const __attribute__((address_space(1))) void*)gpB,
          (__attribute__((address_space(3))) void*)&Bs[c * 512], 16, 0, 0);
    }
    __syncthreads();

    Frag fa[4], fb[4];
    #pragma unroll
    for (int i = 0; i < 4; ++i)
      fa[i].u = *(const uint4*)&As[(wm + 16 * i + (l & 15)) * 32 + (l >> 4) * 8];
    #pragma unroll
    for (int j = 0; j < 4; ++j)
      fb[j].u = *(const uint4*)&Bs[(wn + 16 * j + (l & 15)) * 32 + (l >> 4) * 8];
    #pragma unroll
    for (int i = 0; i < 4; ++i)
      #pragma unroll
      for (int j = 0; j < 4; ++j)
        acc[i][j] = __builtin_amdgcn_mfma_f32_16x16x32_bf16(fa[i].v, fb[j].v, acc[i][j], 0, 0, 0);
    __syncthreads();
  }

  const int q4 = (l >> 4) * 4;
  const int cl = l & 15;
  #pragma unroll
  for (int i = 0; i < 4; ++i) {
    #pragma unroll
    for (int j = 0; j < 4; ++j) {
      const int col = bn + wn + 16 * j + cl;
      const float bs = bias[col];
      #pragma unroll
      for (int r = 0; r < 4; ++r) {
        const int row = bm + wm + 16 * i + q4 + r;
        float o = acc[i][j][r] + bs;
        o = fmaxf(o, 0.f);
        if (OUT_BF16)
          ((unsigned short*)Cout)[(size_t)row * N + col] = f2bf(o);
        else
          ((float*)Cout)[(size_t)row * N + col] = o;
      }
    }
  }
}

// ---------------------------------------------------------------------------
// Tsum[i,j,k,g] = sum_r T[r,i,j,k,g]
__global__ void tsum_kernel(const float* __restrict__ T, float* __restrict__ Tsum)
{
  const int idx = blockIdx.x * 256 + threadIdx.x;
  float s = 0.f;
  #pragma unroll
  for (int r = 0; r < RANK_; ++r) s += T[r * 8192 + idx];
  Tsum[idx] = s;
}

// ---------------------------------------------------------------------------
// Per (b,n): U[q,i,k,g] = sum_j Ts[i,j,k,g]*qn[q,j]; then
// WmatT[b, (q*10+a)*2+g, n*16+i] = bf16( sum_k U[q,i,k,g]*an[a,k] )
__global__ __launch_bounds__(256) void build_w_kernel(
    const float* __restrict__ q_, const float* __restrict__ a_,
    const float* __restrict__ Tsum, unsigned short* __restrict__ WmatT)
{
  const int n = blockIdx.x;   // 0..31
  const int b = blockIdx.y;   // 0..127
  const int t = threadIdx.x;
  __shared__ float Ts[8192];          // [i][j][k][g]
  __shared__ float U[14 * 544];       // [q][i*34 + k*2 + g]

  #pragma unroll
  for (int s = 0; s < 8; ++s)
    ((float4*)Ts)[s * 256 + t] = ((const float4*)Tsum)[s * 256 + t];
  __syncthreads();

  // phase 1: thread owns (i = t>>4, k = t&15), both g
  {
    const int i = t >> 4, k = t & 15;
    float acc0[NQ_], acc1[NQ_];
    #pragma unroll
    for (int q = 0; q < NQ_; ++q) { acc0[q] = 0.f; acc1[q] = 0.f; }
    const float* qbase = q_ + (size_t)b * NQ_ * HDIM + n * 16;
    #pragma unroll
    for (int j = 0; j < 16; ++j) {
      float2 ts = *(const float2*)&Ts[i * 512 + j * 32 + k * 2];
      #pragma unroll
      for (int q = 0; q < NQ_; ++q) {
        float qv = qbase[q * HDIM + j];      // uniform -> s_load
        acc0[q] += ts.x * qv;
        acc1[q] += ts.y * qv;
      }
    }
    #pragma unroll
    for (int q = 0; q < NQ_; ++q) {
      float2 uu; uu.x = acc0[q]; uu.y = acc1[q];
      *(float2*)&U[q * 544 + i * 34 + k * 2] = uu;
    }
  }
  __syncthreads();

  // phase 2: thread owns (q = t>>4, i = t&15), both g; q>=14 idle
  if ((t >> 4) < NQ_) {
    const int q = t >> 4, i = t & 15;
    float acc0[NA_], acc1[NA_];
    #pragma unroll
    for (int a = 0; a < NA_; ++a) { acc0[a] = 0.f; acc1[a] = 0.f; }
    const float* abase = a_ + (size_t)b * NA_ * HDIM + n * 16;
    #pragma unroll
    for (int k = 0; k < 16; ++k) {
      float2 uu = *(const float2*)&U[q * 544 + i * 34 + k * 2];
      #pragma unroll
      for (int a = 0; a < NA_; ++a) {
        float av = abase[a * HDIM + k];      // uniform -> s_load
        acc0[a] += uu.x * av;
        acc1[a] += uu.y * av;
      }
    }
    unsigned short* wb = WmatT + (size_t)b * 288 * 512 + (n * 16 + i);
    #pragma unroll
    for (int a = 0; a < NA_; ++a) {
      wb[(size_t)((q * 10 + a) * 2 + 0) * 512] = f2bf(acc0[a]);
      wb[(size_t)((q * 10 + a) * 2 + 1) * 512] = f2bf(acc1[a]);
    }
  }
}

// ---------------------------------------------------------------------------
// Per b: out[b,100,280] = v_[b,100,512] @ WmatT[b,288,512]^T  (bf16 MFMA)
// One block per b: M=128(pad), N=288(pad), K=512. 8 waves: 4m x 2n.
__global__ __launch_bounds__(512) void final_mfma(
    const unsigned short* __restrict__ Vrb, const unsigned short* __restrict__ WmatT,
    float* __restrict__ out)
{
  __shared__ __align__(16) unsigned short As[128 * 32];   // [m][k]
  __shared__ __align__(16) unsigned short Bs[288 * 32];   // [n][k]
  const int b = blockIdx.x;
  const int t = threadIdx.x;
  const int w = t >> 6, l = t & 63;
  const int wm = (w >> 1) * 32;     // 0,32,64,96
  const int wn = (w & 1) * 144;     // 0,144

  f32x4 acc[2][9];
  #pragma unroll
  for (int mi = 0; mi < 2; ++mi)
    #pragma unroll
    for (int nj = 0; nj < 9; ++nj) acc[mi][nj] = f32x4{0.f, 0.f, 0.f, 0.f};

  const unsigned short* Wb = WmatT + (size_t)b * 288 * 512;

  for (int k0 = 0; k0 < 512; k0 += 32) {
    // stage A: wave w loads rows w*16..w*16+15 -> As[w*512 .. w*512+511]
    {
      int grow = b * NV_ + w * 16 + (l >> 2);
      if (grow > B_ * NV_ - 1) grow = B_ * NV_ - 1;   // clamp pad rows (b=127)
      const unsigned short* src = Vrb + (size_t)grow * HDIM + k0 + (l & 3) * 8;
      __builtin_amdgcn_global_load_lds(
          (const __attribute__((address_space(1))) void*)src,
          (__attribute__((address_space(3))) void*)&As[w * 512], 16, 0, 0);
    }
    // stage B: 1152 x 16B; waves cover 512/pass, tail pass = waves 0..1
    #pragma unroll
    for (int c = 0; c < 3; ++c) {
      const int base = c * 512 + w * 64;
      if (base < 1152) {
        const int li = base + l;
        const int nrow = li >> 2, ko = (li & 3) * 8;
        const unsigned short* src = Wb + (size_t)nrow * 512 + k0 + ko;
        __builtin_amdgcn_global_load_lds(
            (const __attribute__((address_space(1))) void*)src,
            (__attribute__((address_space(3))) void*)&Bs[base * 8], 16, 0, 0);
      }
    }
    __syncthreads();

    Frag fa[2], fb[9];
    #pragma unroll
    for (int mi = 0; mi < 2; ++mi)
      fa[mi].u = *(const uint4*)&As[(wm + mi * 16 + (l & 15)) * 32 + (l >> 4) * 8];
    #pragma unroll
    for (int nj = 0; nj < 9; ++nj)
      fb[nj].u = *(const uint4*)&Bs[(wn + nj * 16 + (l & 15)) * 32 + (l >> 4) * 8];
    #pragma unroll
    for (int mi = 0; mi < 2; ++mi)
      #pragma unroll
      for (int nj = 0; nj < 9; ++nj)
        acc[mi][nj] = __builtin_amdgcn_mfma_f32_16x16x32_bf16(fa[mi].v, fb[nj].v, acc[mi][nj], 0, 0, 0);
    __syncthreads();
  }

  #pragma unroll
  for (int mi = 0; mi < 2; ++mi) {
    #pragma unroll
    for (int nj = 0; nj < 9; ++nj) {
      const int col = wn + nj * 16 + (l & 15);
      if (col < 280) {
        #pragma unroll
        for (int r = 0; r < 4; ++r) {
          const int row = wm + mi * 16 + (l >> 4) * 4 + r;
          if (row < NV_)
            out[((size_t)b * NV_ + row) * 280 + col] = acc[mi][nj][r];
        }
      }
    }
  }
}

// ---------------------------------------------------------------------------
extern "C" void kernel_launch(void* const* d_in, const int* in_sizes, int n_in,
                              void* d_out, int out_size, void* d_ws, size_t ws_size,
                              hipStream_t stream)
{
  const float* v   = (const float*)d_in[0];
  const float* q   = (const float*)d_in[1];
  const float* a   = (const float*)d_in[2];
  const float* Wv  = (const float*)d_in[3];
  const float* bv  = (const float*)d_in[4];
  const float* Wq  = (const float*)d_in[5];
  const float* bq  = (const float*)d_in[6];
  const float* Wa  = (const float*)d_in[7];
  const float* ba  = (const float*)d_in[8];
  const float* Wvr = (const float*)d_in[9];
  const float* bvr = (const float*)d_in[10];
  const float* Wqr = (const float*)d_in[11];
  const float* bqr = (const float*)d_in[12];
  const float* War = (const float*)d_in[13];
  const float* bar = (const float*)d_in[14];
  const float* T   = (const float*)d_in[15];

  float* wsf = (float*)d_ws;
  unsigned short* wsu = (unsigned short*)d_ws;

  // ---- workspace map (ushort units unless noted) ----
  unsigned short* vb    = wsu;              // 26,214,400   (dead after L1 v-gemm)
  unsigned short* qb    = wsu + 26214400;   //  1,835,008
  unsigned short* ab    = wsu + 28049408;   //  1,310,720
  unsigned short* Wvb   = wsu + 29360128;   //  1,048,576
  unsigned short* Wqb   = wsu + 30408704;   //    524,288
  unsigned short* Wab   = wsu + 30932992;   //    524,288
  unsigned short* Wvrb  = wsu + 31457280;   //    262,144
  unsigned short* Wqrb  = wsu + 31719424;   //    262,144
  unsigned short* Warb  = wsu + 31981568;   //    262,144
  unsigned short* vtb   = wsu + 32243712;   //  6,553,600
  unsigned short* qtb   = wsu + 38797312;   //    917,504
  unsigned short* atb   = wsu + 39714816;   //    655,360
  unsigned short* vrb   = wsu + 40370176;   //  6,553,600  (bf16 v_)
  unsigned short* WmatT = wsu;              // 18,874,368  overlays vb
  float* q_r  = wsf + 23461888;             //    917,504 f
  float* a_r  = wsf + 24379392;             //    655,360 f
  float* Tsum = wsf + 25034752;             //      8,192 f

  cvt_kernel<<<15744, 256, 0, stream>>>(v, q, a, Wv, Wq, Wa, Wvr, Wqr, War, wsu);

  // layer 1 (bf16 out)
  gemm_mfma<true><<<dim3(4, 100), 256, 0, stream>>>(vb, Wvb, bv, vtb, 12800, 512, 2048);
  gemm_mfma<true><<<dim3(4, 14),  256, 0, stream>>>(qb, Wqb, bq, qtb,  1792, 512, 1024);
  gemm_mfma<true><<<dim3(4, 10),  256, 0, stream>>>(ab, Wab, ba, atb,  1280, 512, 1024);
  // layer 2: v -> bf16 (feeds final MFMA), q/a -> fp32 (feed build_w)
  gemm_mfma<true> <<<dim3(4, 100), 256, 0, stream>>>(vtb, Wvrb, bvr, vrb, 12800, 512, 512);
  gemm_mfma<false><<<dim3(4, 14),  256, 0, stream>>>(qtb, Wqrb, bqr, q_r,  1792, 512, 512);
  gemm_mfma<false><<<dim3(4, 10),  256, 0, stream>>>(atb, Warb, bar, a_r,  1280, 512, 512);

  tsum_kernel<<<32, 256, 0, stream>>>(T, Tsum);
  build_w_kernel<<<dim3(32, 128), 256, 0, stream>>>(q_r, a_r, Tsum, WmatT);
  final_mfma<<<128, 512, 0, stream>>>(vrb, WmatT, (float*)d_out);
}

// Round 5
// 364.722 us; speedup vs baseline: 3.4732x; 1.1233x over previous
//
#include <hip/hip_runtime.h>
#include <cstddef>
#include <cstdint>

#define B_    128
#define NV_   100
#define NQ_   14
#define NA_   10
#define HDIM  512
#define RANK_ 32
#define HD_   16
#define G_    2

typedef __bf16 bf16x8 __attribute__((ext_vector_type(8)));
typedef float  f32x4  __attribute__((ext_vector_type(4)));
union Frag { uint4 u; bf16x8 v; };

__device__ __forceinline__ unsigned int f2bf(float f) {
  unsigned int u = __float_as_uint(f);
  u = (u + 0x7FFFu + ((u >> 16) & 1u)) >> 16;
  return u & 0xFFFFu;
}

// ---------------------------------------------------------------------------
// fp32 -> bf16 for q, a, and the six weight matrices (NOT v — converted inline
// in l1_gemm). dst is contiguous in this exact order.
__global__ __launch_bounds__(256) void cvt_kernel(
    const float* __restrict__ s0, const float* __restrict__ s1,
    const float* __restrict__ s2, const float* __restrict__ s3,
    const float* __restrict__ s4, const float* __restrict__ s5,
    const float* __restrict__ s6, const float* __restrict__ s7,
    unsigned short* __restrict__ dst)
{
  const int pref[8] = {896, 1536, 2048, 2304, 2560, 2688, 2816, 2944};
  const float* srcs[8] = {s0, s1, s2, s3, s4, s5, s6, s7};
  const int blk = blockIdx.x;
  int seg = 0;
  #pragma unroll
  for (int i = 0; i < 7; ++i) if (blk >= pref[i]) seg = i + 1;
  const int base_chunk = seg ? pref[seg - 1] : 0;
  const size_t loc = (size_t)(blk - base_chunk) * 2048 + threadIdx.x * 8;
  const float* s = srcs[seg] + loc;
  float4 f0 = *(const float4*)s;
  float4 f1 = *(const float4*)(s + 4);
  ushort4 o0, o1;
  o0.x = f2bf(f0.x); o0.y = f2bf(f0.y); o0.z = f2bf(f0.z); o0.w = f2bf(f0.w);
  o1.x = f2bf(f1.x); o1.y = f2bf(f1.y); o1.z = f2bf(f1.z); o1.w = f2bf(f1.w);
  unsigned short* d = dst + (size_t)blk * 2048 + threadIdx.x * 8;
  *(ushort4*)d = o0;
  *(ushort4*)(d + 4) = o1;
}

// ---------------------------------------------------------------------------
// Grouped layer-1 GEMM: blocks 0..399 = v (fp32 A, inline cvt), 400..455 = q,
// 456..495 = a. C = relu(A @ W^T + bias), bf16 out, N=512 for all.
__global__ __launch_bounds__(256) void l1_gemm(
    const float* __restrict__ v,
    const unsigned short* __restrict__ qb, const unsigned short* __restrict__ ab,
    const unsigned short* __restrict__ Wvb, const unsigned short* __restrict__ Wqb,
    const unsigned short* __restrict__ Wab,
    const float* __restrict__ bv, const float* __restrict__ bq,
    const float* __restrict__ ba,
    unsigned short* __restrict__ vtb, unsigned short* __restrict__ qtb,
    unsigned short* __restrict__ atb)
{
  __shared__ __align__(16) unsigned short As[4096];  // [128][32]
  __shared__ __align__(16) unsigned short Bs[4096];
  const int bx = blockIdx.x;
  int grp, gx, gy, K;
  const unsigned short *A16 = qb, *W;
  const float* bias;
  unsigned short* C;
  if (bx < 400)      { grp = 0; gx = bx & 3; gy = bx >> 2;           W = Wvb; bias = bv; C = vtb; K = 2048; }
  else if (bx < 456) { grp = 1; int lo = bx - 400; gx = lo & 3; gy = lo >> 2; A16 = qb; W = Wqb; bias = bq; C = qtb; K = 1024; }
  else               { grp = 2; int lo = bx - 456; gx = lo & 3; gy = lo >> 2; A16 = ab; W = Wab; bias = ba; C = atb; K = 1024; }
  const int bn = gx * 128, bm = gy * 128;
  const int t = threadIdx.x;
  const int w = t >> 6, l = t & 63;
  const int wm = (w >> 1) * 64, wn = (w & 1) * 64;
  const int rr = l >> 2, ko = (l & 3) * 8;

  f32x4 acc[4][4];
  #pragma unroll
  for (int i = 0; i < 4; ++i)
    #pragma unroll
    for (int j = 0; j < 4; ++j) acc[i][j] = f32x4{0.f, 0.f, 0.f, 0.f};

  if (grp == 0) {
    // v path: A is fp32, convert during staging; W via global_load_lds
    const int row = t >> 1, half = t & 1;
    for (int k0 = 0; k0 < 2048; k0 += 32) {
      const float* src = v + (size_t)(bm + row) * 2048 + k0 + half * 16;
      float4 f0 = *(const float4*)(src + 0);
      float4 f1 = *(const float4*)(src + 4);
      float4 f2 = *(const float4*)(src + 8);
      float4 f3 = *(const float4*)(src + 12);
      #pragma unroll
      for (int c2 = 0; c2 < 2; ++c2) {
        const int c = w * 2 + c2;
        const unsigned short* gpB = W + (size_t)(bn + c * 16 + rr) * 2048 + k0 + ko;
        __builtin_amdgcn_global_load_lds(
            (const __attribute__((address_space(1))) void*)gpB,
            (__attribute__((address_space(3))) void*)&Bs[c * 512], 16, 0, 0);
      }
      uint4 p0, p1;
      p0.x = f2bf(f0.x) | (f2bf(f0.y) << 16);
      p0.y = f2bf(f0.z) | (f2bf(f0.w) << 16);
      p0.z = f2bf(f1.x) | (f2bf(f1.y) << 16);
      p0.w = f2bf(f1.z) | (f2bf(f1.w) << 16);
      p1.x = f2bf(f2.x) | (f2bf(f2.y) << 16);
      p1.y = f2bf(f2.z) | (f2bf(f2.w) << 16);
      p1.z = f2bf(f3.x) | (f2bf(f3.y) << 16);
      p1.w = f2bf(f3.z) | (f2bf(f3.w) << 16);
      *(uint4*)&As[row * 32 + half * 16]     = p0;
      *(uint4*)&As[row * 32 + half * 16 + 8] = p1;
      __syncthreads();
      Frag fa[4], fb[4];
      #pragma unroll
      for (int i = 0; i < 4; ++i)
        fa[i].u = *(const uint4*)&As[(wm + 16 * i + (l & 15)) * 32 + (l >> 4) * 8];
      #pragma unroll
      for (int j = 0; j < 4; ++j)
        fb[j].u = *(const uint4*)&Bs[(wn + 16 * j + (l & 15)) * 32 + (l >> 4) * 8];
      #pragma unroll
      for (int i = 0; i < 4; ++i)
        #pragma unroll
        for (int j = 0; j < 4; ++j)
          acc[i][j] = __builtin_amdgcn_mfma_f32_16x16x32_bf16(fa[i].v, fb[j].v, acc[i][j], 0, 0, 0);
      __syncthreads();
    }
  } else {
    for (int k0 = 0; k0 < K; k0 += 32) {
      #pragma unroll
      for (int c2 = 0; c2 < 2; ++c2) {
        const int c = w * 2 + c2;
        const unsigned short* gpA = A16 + (size_t)(bm + c * 16 + rr) * K + k0 + ko;
        const unsigned short* gpB = W   + (size_t)(bn + c * 16 + rr) * K + k0 + ko;
        __builtin_amdgcn_global_load_lds(
            (const __attribute__((address_space(1))) void*)gpA,
            (__attribute__((address_space(3))) void*)&As[c * 512], 16, 0, 0);
        __builtin_amdgcn_global_load_lds(
            (const __attribute__((address_space(1))) void*)gpB,
            (__attribute__((address_space(3))) void*)&Bs[c * 512], 16, 0, 0);
      }
      __syncthreads();
      Frag fa[4], fb[4];
      #pragma unroll
      for (int i = 0; i < 4; ++i)
        fa[i].u = *(const uint4*)&As[(wm + 16 * i + (l & 15)) * 32 + (l >> 4) * 8];
      #pragma unroll
      for (int j = 0; j < 4; ++j)
        fb[j].u = *(const uint4*)&Bs[(wn + 16 * j + (l & 15)) * 32 + (l >> 4) * 8];
      #pragma unroll
      for (int i = 0; i < 4; ++i)
        #pragma unroll
        for (int j = 0; j < 4; ++j)
          acc[i][j] = __builtin_amdgcn_mfma_f32_16x16x32_bf16(fa[i].v, fb[j].v, acc[i][j], 0, 0, 0);
      __syncthreads();
    }
  }

  const int q4 = (l >> 4) * 4, cl = l & 15;
  #pragma unroll
  for (int i = 0; i < 4; ++i)
    #pragma unroll
    for (int j = 0; j < 4; ++j) {
      const int col = bn + wn + 16 * j + cl;
      const float bs = bias[col];
      #pragma unroll
      for (int r = 0; r < 4; ++r) {
        const int row = bm + wm + 16 * i + q4 + r;
        float o = fmaxf(acc[i][j][r] + bs, 0.f);
        C[(size_t)row * 512 + col] = (unsigned short)f2bf(o);
      }
    }
}

// ---------------------------------------------------------------------------
// Grouped layer-2 GEMM: K=512 for all; v out bf16, q/a out fp32.
__global__ __launch_bounds__(256) void l2_gemm(
    const unsigned short* __restrict__ vtb, const unsigned short* __restrict__ qtb,
    const unsigned short* __restrict__ atb,
    const unsigned short* __restrict__ Wvrb, const unsigned short* __restrict__ Wqrb,
    const unsigned short* __restrict__ Warb,
    const float* __restrict__ bvr, const float* __restrict__ bqr,
    const float* __restrict__ bar,
    unsigned short* __restrict__ vrb, float* __restrict__ q_r, float* __restrict__ a_r)
{
  __shared__ __align__(16) unsigned short As[4096];
  __shared__ __align__(16) unsigned short Bs[4096];
  const int bx = blockIdx.x;
  int grp, gx, gy;
  const unsigned short *A16, *W;
  const float* bias;
  if (bx < 400)      { grp = 0; gx = bx & 3; gy = bx >> 2;           A16 = vtb; W = Wvrb; bias = bvr; }
  else if (bx < 456) { grp = 1; int lo = bx - 400; gx = lo & 3; gy = lo >> 2; A16 = qtb; W = Wqrb; bias = bqr; }
  else               { grp = 2; int lo = bx - 456; gx = lo & 3; gy = lo >> 2; A16 = atb; W = Warb; bias = bar; }
  const int bn = gx * 128, bm = gy * 128;
  const int t = threadIdx.x;
  const int w = t >> 6, l = t & 63;
  const int wm = (w >> 1) * 64, wn = (w & 1) * 64;
  const int rr = l >> 2, ko = (l & 3) * 8;

  f32x4 acc[4][4];
  #pragma unroll
  for (int i = 0; i < 4; ++i)
    #pragma unroll
    for (int j = 0; j < 4; ++j) acc[i][j] = f32x4{0.f, 0.f, 0.f, 0.f};

  for (int k0 = 0; k0 < 512; k0 += 32) {
    #pragma unroll
    for (int c2 = 0; c2 < 2; ++c2) {
      const int c = w * 2 + c2;
      const unsigned short* gpA = A16 + (size_t)(bm + c * 16 + rr) * 512 + k0 + ko;
      const unsigned short* gpB = W   + (size_t)(bn + c * 16 + rr) * 512 + k0 + ko;
      __builtin_amdgcn_global_load_lds(
          (const __attribute__((address_space(1))) void*)gpA,
          (__attribute__((address_space(3))) void*)&As[c * 512], 16, 0, 0);
      __builtin_amdgcn_global_load_lds(
          (const __attribute__((address_space(1))) void*)gpB,
          (__attribute__((address_space(3))) void*)&Bs[c * 512], 16, 0, 0);
    }
    __syncthreads();
    Frag fa[4], fb[4];
    #pragma unroll
    for (int i = 0; i < 4; ++i)
      fa[i].u = *(const uint4*)&As[(wm + 16 * i + (l & 15)) * 32 + (l >> 4) * 8];
    #pragma unroll
    for (int j = 0; j < 4; ++j)
      fb[j].u = *(const uint4*)&Bs[(wn + 16 * j + (l & 15)) * 32 + (l >> 4) * 8];
    #pragma unroll
    for (int i = 0; i < 4; ++i)
      #pragma unroll
      for (int j = 0; j < 4; ++j)
        acc[i][j] = __builtin_amdgcn_mfma_f32_16x16x32_bf16(fa[i].v, fb[j].v, acc[i][j], 0, 0, 0);
    __syncthreads();
  }

  const int q4 = (l >> 4) * 4, cl = l & 15;
  #pragma unroll
  for (int i = 0; i < 4; ++i)
    #pragma unroll
    for (int j = 0; j < 4; ++j) {
      const int col = bn + wn + 16 * j + cl;
      const float bs = bias[col];
      #pragma unroll
      for (int r = 0; r < 4; ++r) {
        const int row = bm + wm + 16 * i + q4 + r;
        float o = fmaxf(acc[i][j][r] + bs, 0.f);
        if (grp == 0)      vrb[(size_t)row * 512 + col] = (unsigned short)f2bf(o);
        else if (grp == 1) q_r[(size_t)row * 512 + col] = o;
        else               a_r[(size_t)row * 512 + col] = o;
      }
    }
}

// ---------------------------------------------------------------------------
__global__ void tsum_kernel(const float* __restrict__ T, float* __restrict__ Tsum)
{
  const int idx = blockIdx.x * 256 + threadIdx.x;
  float s = 0.f;
  #pragma unroll
  for (int r = 0; r < RANK_; ++r) s += T[r * 8192 + idx];
  Tsum[idx] = s;
}

// ---------------------------------------------------------------------------
// Per (b,n): U = Tsum x q_ ; WmatT[b, col, n*16+i] = bf16(U x a_)
// WmatT padded to 320 rows (cols 280..319 unwritten).
__global__ __launch_bounds__(256) void build_w_kernel(
    const float* __restrict__ q_, const float* __restrict__ a_,
    const float* __restrict__ Tsum, unsigned short* __restrict__ WmatT)
{
  const int n = blockIdx.x, b = blockIdx.y, t = threadIdx.x;
  __shared__ float Ts[8192];
  __shared__ float U[14 * 544];

  #pragma unroll
  for (int s = 0; s < 8; ++s)
    ((float4*)Ts)[s * 256 + t] = ((const float4*)Tsum)[s * 256 + t];
  __syncthreads();

  {
    const int i = t >> 4, k = t & 15;
    float acc0[NQ_], acc1[NQ_];
    #pragma unroll
    for (int q = 0; q < NQ_; ++q) { acc0[q] = 0.f; acc1[q] = 0.f; }
    const float* qbase = q_ + (size_t)b * NQ_ * HDIM + n * 16;
    #pragma unroll
    for (int j = 0; j < 16; ++j) {
      float2 ts = *(const float2*)&Ts[i * 512 + j * 32 + k * 2];
      #pragma unroll
      for (int q = 0; q < NQ_; ++q) {
        float qv = qbase[q * HDIM + j];
        acc0[q] += ts.x * qv;
        acc1[q] += ts.y * qv;
      }
    }
    #pragma unroll
    for (int q = 0; q < NQ_; ++q) {
      float2 uu; uu.x = acc0[q]; uu.y = acc1[q];
      *(float2*)&U[q * 544 + i * 34 + k * 2] = uu;
    }
  }
  __syncthreads();

  if ((t >> 4) < NQ_) {
    const int q = t >> 4, i = t & 15;
    float acc0[NA_], acc1[NA_];
    #pragma unroll
    for (int a = 0; a < NA_; ++a) { acc0[a] = 0.f; acc1[a] = 0.f; }
    const float* abase = a_ + (size_t)b * NA_ * HDIM + n * 16;
    #pragma unroll
    for (int k = 0; k < 16; ++k) {
      float2 uu = *(const float2*)&U[q * 544 + i * 34 + k * 2];
      #pragma unroll
      for (int a = 0; a < NA_; ++a) {
        float av = abase[a * HDIM + k];
        acc0[a] += uu.x * av;
        acc1[a] += uu.y * av;
      }
    }
    unsigned short* wb = WmatT + (size_t)b * 320 * 512 + (n * 16 + i);
    #pragma unroll
    for (int a = 0; a < NA_; ++a) {
      wb[(size_t)((q * 10 + a) * 2 + 0) * 512] = (unsigned short)f2bf(acc0[a]);
      wb[(size_t)((q * 10 + a) * 2 + 1) * 512] = (unsigned short)f2bf(acc1[a]);
    }
  }
}

// ---------------------------------------------------------------------------
// out[b,100,280] = v_[b,100,512] @ WmatT[b,320,512]^T; grid (2 n-halves, 128 b)
__global__ __launch_bounds__(512) void final_mfma(
    const unsigned short* __restrict__ Vrb, const unsigned short* __restrict__ WmatT,
    float* __restrict__ out)
{
  __shared__ __align__(16) unsigned short As[128 * 32];   // 8 KB
  __shared__ __align__(16) unsigned short Bs[160 * 32];   // 10 KB
  const int b  = blockIdx.y;
  const int n0 = blockIdx.x * 160;
  const int t = threadIdx.x;
  const int w = t >> 6, l = t & 63;
  const int wm = (w >> 1) * 32;   // 0,32,64,96
  const int wn = (w & 1) * 80;    // 0,80

  f32x4 acc[2][5];
  #pragma unroll
  for (int mi = 0; mi < 2; ++mi)
    #pragma unroll
    for (int nj = 0; nj < 5; ++nj) acc[mi][nj] = f32x4{0.f, 0.f, 0.f, 0.f};

  const unsigned short* Wb = WmatT + (size_t)b * 320 * 512;

  for (int k0 = 0; k0 < 512; k0 += 32) {
    {
      int grow = b * NV_ + w * 16 + (l >> 2);
      if (grow > B_ * NV_ - 1) grow = B_ * NV_ - 1;
      const unsigned short* src = Vrb + (size_t)grow * HDIM + k0 + (l & 3) * 8;
      __builtin_amdgcn_global_load_lds(
          (const __attribute__((address_space(1))) void*)src,
          (__attribute__((address_space(3))) void*)&As[w * 512], 16, 0, 0);
    }
    #pragma unroll
    for (int c = 0; c < 2; ++c) {
      const int base = c * 512 + w * 64;
      if (base < 640) {
        const int li = base + l;
        const int nrow = li >> 2, ko2 = (li & 3) * 8;
        const unsigned short* src = Wb + (size_t)(n0 + nrow) * 512 + k0 + ko2;
        __builtin_amdgcn_global_load_lds(
            (const __attribute__((address_space(1))) void*)src,
            (__attribute__((address_space(3))) void*)&Bs[base * 8], 16, 0, 0);
      }
    }
    __syncthreads();

    Frag fa[2], fb[5];
    #pragma unroll
    for (int mi = 0; mi < 2; ++mi)
      fa[mi].u = *(const uint4*)&As[(wm + mi * 16 + (l & 15)) * 32 + (l >> 4) * 8];
    #pragma unroll
    for (int nj = 0; nj < 5; ++nj)
      fb[nj].u = *(const uint4*)&Bs[(wn + nj * 16 + (l & 15)) * 32 + (l >> 4) * 8];
    #pragma unroll
    for (int mi = 0; mi < 2; ++mi)
      #pragma unroll
      for (int nj = 0; nj < 5; ++nj)
        acc[mi][nj] = __builtin_amdgcn_mfma_f32_16x16x32_bf16(fa[mi].v, fb[nj].v, acc[mi][nj], 0, 0, 0);
    __syncthreads();
  }

  #pragma unroll
  for (int mi = 0; mi < 2; ++mi)
    #pragma unroll
    for (int nj = 0; nj < 5; ++nj) {
      const int col = n0 + wn + nj * 16 + (l & 15);
      if (col < 280) {
        #pragma unroll
        for (int r = 0; r < 4; ++r) {
          const int row = wm + mi * 16 + (l >> 4) * 4 + r;
          if (row < NV_)
            out[((size_t)b * NV_ + row) * 280 + col] = acc[mi][nj][r];
        }
      }
    }
}

// ---------------------------------------------------------------------------
extern "C" void kernel_launch(void* const* d_in, const int* in_sizes, int n_in,
                              void* d_out, int out_size, void* d_ws, size_t ws_size,
                              hipStream_t stream)
{
  const float* v   = (const float*)d_in[0];
  const float* q   = (const float*)d_in[1];
  const float* a   = (const float*)d_in[2];
  const float* Wv  = (const float*)d_in[3];
  const float* bv  = (const float*)d_in[4];
  const float* Wq  = (const float*)d_in[5];
  const float* bq  = (const float*)d_in[6];
  const float* Wa  = (const float*)d_in[7];
  const float* ba  = (const float*)d_in[8];
  const float* Wvr = (const float*)d_in[9];
  const float* bvr = (const float*)d_in[10];
  const float* Wqr = (const float*)d_in[11];
  const float* bqr = (const float*)d_in[12];
  const float* War = (const float*)d_in[13];
  const float* bar = (const float*)d_in[14];
  const float* T   = (const float*)d_in[15];

  unsigned short* wsu = (unsigned short*)d_ws;
  float* wsf = (float*)d_ws;

  // region A (ushort): WmatT [0 .. 20,971,520) — early overlay: bf16 q/a/weights
  unsigned short* WmatT = wsu;
  unsigned short* qb    = wsu;              //  1,835,008 (dead after l1)
  unsigned short* ab    = wsu + 1835008;    //  1,310,720 (dead after l1)
  unsigned short* Wvb   = wsu + 3145728;    //  1,048,576 (dead after l1)
  unsigned short* Wqb   = wsu + 4194304;    //    524,288
  unsigned short* Wab   = wsu + 4718592;    //    524,288
  unsigned short* Wvrb  = wsu + 5242880;    //    262,144 (dead after l2)
  unsigned short* Wqrb  = wsu + 5505024;    //    262,144
  unsigned short* Warb  = wsu + 5767168;    //    262,144  end 6,029,312 < 20.97M ok
  // persistent bf16 intermediates
  unsigned short* vtb   = wsu + 20971520;   //  6,553,600
  unsigned short* qtb   = wsu + 27525120;   //    917,504
  unsigned short* atb   = wsu + 28442624;   //    655,360
  unsigned short* vrb   = wsu + 29097984;   //  6,553,600  end 35,651,584 ush
  // fp32 region
  float* q_r  = wsf + 17825792;             //    917,504 f
  float* a_r  = wsf + 18743296;             //    655,360 f
  float* Tsum = wsf + 19398656;             //      8,192 f   (end 77.6 MB)

  cvt_kernel<<<2944, 256, 0, stream>>>(q, a, Wv, Wq, Wa, Wvr, Wqr, War, wsu);

  l1_gemm<<<496, 256, 0, stream>>>(v, qb, ab, Wvb, Wqb, Wab, bv, bq, ba,
                                   vtb, qtb, atb);
  l2_gemm<<<496, 256, 0, stream>>>(vtb, qtb, atb, Wvrb, Wqrb, Warb,
                                   bvr, bqr, bar, vrb, q_r, a_r);

  tsum_kernel<<<32, 256, 0, stream>>>(T, Tsum);
  build_w_kernel<<<dim3(32, 128), 256, 0, stream>>>(q_r, a_r, Tsum, WmatT);
  final_mfma<<<dim3(2, 128), 512, 0, stream>>>(vrb, WmatT, (float*)d_out);
}

// Round 7
// 354.491 us; speedup vs baseline: 3.5735x; 1.0289x over previous
//
#include <hip/hip_runtime.h>
#include <cstddef>
#include <cstdint>

#define B_    128
#define NV_   100
#define NQ_   14
#define NA_   10
#define HDIM  512
#define RANK_ 32
#define HD_   16
#define G_    2

typedef __bf16 bf16x8 __attribute__((ext_vector_type(8)));
typedef float  f32x4  __attribute__((ext_vector_type(4)));
union Frag { uint4 u; bf16x8 v; };

__device__ __forceinline__ unsigned int f2bf(float f) {
  unsigned int u = __float_as_uint(f);
  u = (u + 0x7FFFu + ((u >> 16) & 1u)) >> 16;
  return u & 0xFFFFu;
}

// ---------------------------------------------------------------------------
// fp32 -> bf16 for q, a, and the six weight matrices (NOT v — converted inline
// in l1_gemm). dst is contiguous in this exact order.
__global__ __launch_bounds__(256) void cvt_kernel(
    const float* __restrict__ s0, const float* __restrict__ s1,
    const float* __restrict__ s2, const float* __restrict__ s3,
    const float* __restrict__ s4, const float* __restrict__ s5,
    const float* __restrict__ s6, const float* __restrict__ s7,
    unsigned short* __restrict__ dst)
{
  const int pref[8] = {896, 1536, 2048, 2304, 2560, 2688, 2816, 2944};
  const float* srcs[8] = {s0, s1, s2, s3, s4, s5, s6, s7};
  const int blk = blockIdx.x;
  int seg = 0;
  #pragma unroll
  for (int i = 0; i < 7; ++i) if (blk >= pref[i]) seg = i + 1;
  const int base_chunk = seg ? pref[seg - 1] : 0;
  const size_t loc = (size_t)(blk - base_chunk) * 2048 + threadIdx.x * 8;
  const float* s = srcs[seg] + loc;
  float4 f0 = *(const float4*)s;
  float4 f1 = *(const float4*)(s + 4);
  ushort4 o0, o1;
  o0.x = f2bf(f0.x); o0.y = f2bf(f0.y); o0.z = f2bf(f0.z); o0.w = f2bf(f0.w);
  o1.x = f2bf(f1.x); o1.y = f2bf(f1.y); o1.z = f2bf(f1.z); o1.w = f2bf(f1.w);
  unsigned short* d = dst + (size_t)blk * 2048 + threadIdx.x * 8;
  *(ushort4*)d = o0;
  *(ushort4*)(d + 4) = o1;
}

// ---------------------------------------------------------------------------
// Grouped layer-1 GEMM, 64x128 tiles. v-group = 800 blocks (200 gy x 4 gx),
// XCD-swizzled: xcd = bx&7, gy = xcd*25 + (j>>2), gx = j&3  (j = bx>>3, 0..99)
// so the 4 n-tiles of one gy run consecutively on one XCD (L2 reuse of v rows).
__global__ __launch_bounds__(256) void l1_gemm(
    const float* __restrict__ v,
    const unsigned short* __restrict__ qb, const unsigned short* __restrict__ ab,
    const unsigned short* __restrict__ Wvb, const unsigned short* __restrict__ Wqb,
    const unsigned short* __restrict__ Wab,
    const float* __restrict__ bv, const float* __restrict__ bq,
    const float* __restrict__ ba,
    unsigned short* __restrict__ vtb, unsigned short* __restrict__ qtb,
    unsigned short* __restrict__ atb)
{
  __shared__ __align__(16) unsigned short As[2048];  // [64][32]
  __shared__ __align__(16) unsigned short Bs[4096];  // [128][32]
  const int bx = blockIdx.x;
  int grp, gx, gy, K;
  const unsigned short *A16 = qb, *W;
  const float* bias;
  unsigned short* C;
  if (bx < 800) {        // v: 200 gy x 4 gx, XCD-swizzled
    grp = 0; const int xcd = bx & 7; const int j = bx >> 3;   // j: 0..99
    gy = xcd * 25 + (j >> 2); gx = j & 3;                     // gy: 0..199
    W = Wvb; bias = bv; C = vtb; K = 2048;
  } else if (bx < 912) {  // q: 28 gy x 4 gx
    grp = 1; const int lo = bx - 800; gy = lo >> 2; gx = lo & 3;
    A16 = qb; W = Wqb; bias = bq; C = qtb; K = 1024;
  } else {                // a: 20 gy x 4 gx
    grp = 2; const int lo = bx - 912; gy = lo >> 2; gx = lo & 3;
    A16 = ab; W = Wab; bias = ba; C = atb; K = 1024;
  }
  const int bm = gy * 64, bn = gx * 128;
  const int t = threadIdx.x;
  const int w = t >> 6, l = t & 63;
  const int wm = (w >> 1) * 32, wn = (w & 1) * 64;
  const int rr = l >> 2, ko = (l & 3) * 8;

  f32x4 acc[2][4];
  #pragma unroll
  for (int i = 0; i < 2; ++i)
    #pragma unroll
    for (int j = 0; j < 4; ++j) acc[i][j] = f32x4{0.f, 0.f, 0.f, 0.f};

  if (grp == 0) {
    const int row = t >> 2, koff = (t & 3) * 8;   // 64 rows x 8 floats
    for (int k0 = 0; k0 < 2048; k0 += 32) {
      const float* src = v + (size_t)(bm + row) * 2048 + k0 + koff;
      float4 f0 = *(const float4*)(src + 0);
      float4 f1 = *(const float4*)(src + 4);
      #pragma unroll
      for (int c2 = 0; c2 < 2; ++c2) {
        const int c = w * 2 + c2;   // 8 chunks of 16 rows
        const unsigned short* gpB = W + (size_t)(bn + c * 16 + rr) * 2048 + k0 + ko;
        __builtin_amdgcn_global_load_lds(
            (const __attribute__((address_space(1))) void*)gpB,
            (__attribute__((address_space(3))) void*)&Bs[c * 512], 16, 0, 0);
      }
      uint4 p;
      p.x = f2bf(f0.x) | (f2bf(f0.y) << 16);
      p.y = f2bf(f0.z) | (f2bf(f0.w) << 16);
      p.z = f2bf(f1.x) | (f2bf(f1.y) << 16);
      p.w = f2bf(f1.z) | (f2bf(f1.w) << 16);
      *(uint4*)&As[row * 32 + koff] = p;
      __syncthreads();
      Frag fa[2], fb[4];
      #pragma unroll
      for (int i = 0; i < 2; ++i)
        fa[i].u = *(const uint4*)&As[(wm + 16 * i + (l & 15)) * 32 + (l >> 4) * 8];
      #pragma unroll
      for (int j = 0; j < 4; ++j)
        fb[j].u = *(const uint4*)&Bs[(wn + 16 * j + (l & 15)) * 32 + (l >> 4) * 8];
      #pragma unroll
      for (int i = 0; i < 2; ++i)
        #pragma unroll
        for (int j = 0; j < 4; ++j)
          acc[i][j] = __builtin_amdgcn_mfma_f32_16x16x32_bf16(fa[i].v, fb[j].v, acc[i][j], 0, 0, 0);
      __syncthreads();
    }
  } else {
    for (int k0 = 0; k0 < K; k0 += 32) {
      {
        const unsigned short* gpA = A16 + (size_t)(bm + w * 16 + rr) * K + k0 + ko;
        __builtin_amdgcn_global_load_lds(
            (const __attribute__((address_space(1))) void*)gpA,
            (__attribute__((address_space(3))) void*)&As[w * 512], 16, 0, 0);
      }
      #pragma unroll
      for (int c2 = 0; c2 < 2; ++c2) {
        const int c = w * 2 + c2;
        const unsigned short* gpB = W + (size_t)(bn + c * 16 + rr) * K + k0 + ko;
        __builtin_amdgcn_global_load_lds(
            (const __attribute__((address_space(1))) void*)gpB,
            (__attribute__((address_space(3))) void*)&Bs[c * 512], 16, 0, 0);
      }
      __syncthreads();
      Frag fa[2], fb[4];
      #pragma unroll
      for (int i = 0; i < 2; ++i)
        fa[i].u = *(const uint4*)&As[(wm + 16 * i + (l & 15)) * 32 + (l >> 4) * 8];
      #pragma unroll
      for (int j = 0; j < 4; ++j)
        fb[j].u = *(const uint4*)&Bs[(wn + 16 * j + (l & 15)) * 32 + (l >> 4) * 8];
      #pragma unroll
      for (int i = 0; i < 2; ++i)
        #pragma unroll
        for (int j = 0; j < 4; ++j)
          acc[i][j] = __builtin_amdgcn_mfma_f32_16x16x32_bf16(fa[i].v, fb[j].v, acc[i][j], 0, 0, 0);
      __syncthreads();
    }
  }

  const int q4 = (l >> 4) * 4, cl = l & 15;
  #pragma unroll
  for (int i = 0; i < 2; ++i)
    #pragma unroll
    for (int j = 0; j < 4; ++j) {
      const int col = bn + wn + 16 * j + cl;
      const float bs = bias[col];
      #pragma unroll
      for (int r = 0; r < 4; ++r) {
        const int row = bm + wm + 16 * i + q4 + r;
        float o = fmaxf(acc[i][j][r] + bs, 0.f);
        C[(size_t)row * 512 + col] = (unsigned short)f2bf(o);
      }
    }
}

// ---------------------------------------------------------------------------
// Grouped layer-2 GEMM, 64x128 tiles, K=512. v out bf16, q/a out fp32.
__global__ __launch_bounds__(256) void l2_gemm(
    const unsigned short* __restrict__ vtb, const unsigned short* __restrict__ qtb,
    const unsigned short* __restrict__ atb,
    const unsigned short* __restrict__ Wvrb, const unsigned short* __restrict__ Wqrb,
    const unsigned short* __restrict__ Warb,
    const float* __restrict__ bvr, const float* __restrict__ bqr,
    const float* __restrict__ bar,
    unsigned short* __restrict__ vrb, float* __restrict__ q_r, float* __restrict__ a_r)
{
  __shared__ __align__(16) unsigned short As[2048];
  __shared__ __align__(16) unsigned short Bs[4096];
  const int bx = blockIdx.x;
  int grp, gx, gy;
  const unsigned short *A16, *W;
  const float* bias;
  if (bx < 800) {
    grp = 0; const int xcd = bx & 7; const int j = bx >> 3;   // j: 0..99
    gy = xcd * 25 + (j >> 2); gx = j & 3;                     // gy: 0..199
    A16 = vtb; W = Wvrb; bias = bvr;
  } else if (bx < 912) {
    grp = 1; const int lo = bx - 800; gy = lo >> 2; gx = lo & 3;
    A16 = qtb; W = Wqrb; bias = bqr;
  } else {
    grp = 2; const int lo = bx - 912; gy = lo >> 2; gx = lo & 3;
    A16 = atb; W = Warb; bias = bar;
  }
  const int bm = gy * 64, bn = gx * 128;
  const int t = threadIdx.x;
  const int w = t >> 6, l = t & 63;
  const int wm = (w >> 1) * 32, wn = (w & 1) * 64;
  const int rr = l >> 2, ko = (l & 3) * 8;

  f32x4 acc[2][4];
  #pragma unroll
  for (int i = 0; i < 2; ++i)
    #pragma unroll
    for (int j = 0; j < 4; ++j) acc[i][j] = f32x4{0.f, 0.f, 0.f, 0.f};

  for (int k0 = 0; k0 < 512; k0 += 32) {
    {
      const unsigned short* gpA = A16 + (size_t)(bm + w * 16 + rr) * 512 + k0 + ko;
      __builtin_amdgcn_global_load_lds(
          (const __attribute__((address_space(1))) void*)gpA,
          (__attribute__((address_space(3))) void*)&As[w * 512], 16, 0, 0);
    }
    #pragma unroll
    for (int c2 = 0; c2 < 2; ++c2) {
      const int c = w * 2 + c2;
      const unsigned short* gpB = W + (size_t)(bn + c * 16 + rr) * 512 + k0 + ko;
      __builtin_amdgcn_global_load_lds(
          (const __attribute__((address_space(1))) void*)gpB,
          (__attribute__((address_space(3))) void*)&Bs[c * 512], 16, 0, 0);
    }
    __syncthreads();
    Frag fa[2], fb[4];
    #pragma unroll
    for (int i = 0; i < 2; ++i)
      fa[i].u = *(const uint4*)&As[(wm + 16 * i + (l & 15)) * 32 + (l >> 4) * 8];
    #pragma unroll
    for (int j = 0; j < 4; ++j)
      fb[j].u = *(const uint4*)&Bs[(wn + 16 * j + (l & 15)) * 32 + (l >> 4) * 8];
    #pragma unroll
    for (int i = 0; i < 2; ++i)
      #pragma unroll
      for (int j = 0; j < 4; ++j)
        acc[i][j] = __builtin_amdgcn_mfma_f32_16x16x32_bf16(fa[i].v, fb[j].v, acc[i][j], 0, 0, 0);
    __syncthreads();
  }

  const int q4 = (l >> 4) * 4, cl = l & 15;
  #pragma unroll
  for (int i = 0; i < 2; ++i)
    #pragma unroll
    for (int j = 0; j < 4; ++j) {
      const int col = bn + wn + 16 * j + cl;
      const float bs = bias[col];
      #pragma unroll
      for (int r = 0; r < 4; ++r) {
        const int row = bm + wm + 16 * i + q4 + r;
        float o = fmaxf(acc[i][j][r] + bs, 0.f);
        if (grp == 0)      vrb[(size_t)row * 512 + col] = (unsigned short)f2bf(o);
        else if (grp == 1) q_r[(size_t)row * 512 + col] = o;
        else               a_r[(size_t)row * 512 + col] = o;
      }
    }
}

// ---------------------------------------------------------------------------
__global__ void tsum_kernel(const float* __restrict__ T, float* __restrict__ Tsum)
{
  const int idx = blockIdx.x * 256 + threadIdx.x;
  float s = 0.f;
  #pragma unroll
  for (int r = 0; r < RANK_; ++r) s += T[r * 8192 + idx];
  Tsum[idx] = s;
}

// ---------------------------------------------------------------------------
// Per (b,n): U = Tsum x q_ ; WmatT[b, col, n*16+i] = bf16(U x a_)
// WmatT padded to 320 rows (cols 280..319 unwritten).
__global__ __launch_bounds__(256) void build_w_kernel(
    const float* __restrict__ q_, const float* __restrict__ a_,
    const float* __restrict__ Tsum, unsigned short* __restrict__ WmatT)
{
  const int n = blockIdx.x, b = blockIdx.y, t = threadIdx.x;
  __shared__ float Ts[8192];
  __shared__ float U[14 * 544];

  #pragma unroll
  for (int s = 0; s < 8; ++s)
    ((float4*)Ts)[s * 256 + t] = ((const float4*)Tsum)[s * 256 + t];
  __syncthreads();

  {
    const int i = t >> 4, k = t & 15;
    float acc0[NQ_], acc1[NQ_];
    #pragma unroll
    for (int q = 0; q < NQ_; ++q) { acc0[q] = 0.f; acc1[q] = 0.f; }
    const float* qbase = q_ + (size_t)b * NQ_ * HDIM + n * 16;
    #pragma unroll
    for (int j = 0; j < 16; ++j) {
      float2 ts = *(const float2*)&Ts[i * 512 + j * 32 + k * 2];
      #pragma unroll
      for (int q = 0; q < NQ_; ++q) {
        float qv = qbase[q * HDIM + j];
        acc0[q] += ts.x * qv;
        acc1[q] += ts.y * qv;
      }
    }
    #pragma unroll
    for (int q = 0; q < NQ_; ++q) {
      float2 uu; uu.x = acc0[q]; uu.y = acc1[q];
      *(float2*)&U[q * 544 + i * 34 + k * 2] = uu;
    }
  }
  __syncthreads();

  if ((t >> 4) < NQ_) {
    const int q = t >> 4, i = t & 15;
    float acc0[NA_], acc1[NA_];
    #pragma unroll
    for (int a = 0; a < NA_; ++a) { acc0[a] = 0.f; acc1[a] = 0.f; }
    const float* abase = a_ + (size_t)b * NA_ * HDIM + n * 16;
    #pragma unroll
    for (int k = 0; k < 16; ++k) {
      float2 uu = *(const float2*)&U[q * 544 + i * 34 + k * 2];
      #pragma unroll
      for (int a = 0; a < NA_; ++a) {
        float av = abase[a * HDIM + k];
        acc0[a] += uu.x * av;
        acc1[a] += uu.y * av;
      }
    }
    unsigned short* wb = WmatT + (size_t)b * 320 * 512 + (n * 16 + i);
    #pragma unroll
    for (int a = 0; a < NA_; ++a) {
      wb[(size_t)((q * 10 + a) * 2 + 0) * 512] = (unsigned short)f2bf(acc0[a]);
      wb[(size_t)((q * 10 + a) * 2 + 1) * 512] = (unsigned short)f2bf(acc1[a]);
    }
  }
}

// ---------------------------------------------------------------------------
// out[b,100,280] = v_[b,100,512] @ WmatT[b,320,512]^T
// grid (4, 128): blockIdx.x = mh*2 + nh; 64-row m-tile, 160-col n-tile.
__global__ __launch_bounds__(256) void final_mfma(
    const unsigned short* __restrict__ Vrb, const unsigned short* __restrict__ WmatT,
    float* __restrict__ out)
{
  __shared__ __align__(16) unsigned short As[2048];   // [64][32]
  __shared__ __align__(16) unsigned short Bs[5120];   // [160][32]
  const int b  = blockIdx.y;
  const int mh = blockIdx.x >> 1;
  const int n0 = (blockIdx.x & 1) * 160;
  const int t = threadIdx.x;
  const int w = t >> 6, l = t & 63;
  const int wm = (w >> 1) * 32;   // 0,32 within 64-row tile
  const int wn = (w & 1) * 80;    // 0,80 within 160-col tile

  f32x4 acc[2][5];
  #pragma unroll
  for (int mi = 0; mi < 2; ++mi)
    #pragma unroll
    for (int nj = 0; nj < 5; ++nj) acc[mi][nj] = f32x4{0.f, 0.f, 0.f, 0.f};

  const unsigned short* Wb = WmatT + (size_t)b * 320 * 512;

  for (int k0 = 0; k0 < 512; k0 += 32) {
    {
      int grow = b * NV_ + mh * 64 + w * 16 + (l >> 2);
      if (grow > B_ * NV_ - 1) grow = B_ * NV_ - 1;   // clamp pad rows
      const unsigned short* src = Vrb + (size_t)grow * HDIM + k0 + (l & 3) * 8;
      __builtin_amdgcn_global_load_lds(
          (const __attribute__((address_space(1))) void*)src,
          (__attribute__((address_space(3))) void*)&As[w * 512], 16, 0, 0);
    }
    #pragma unroll
    for (int c = 0; c < 3; ++c) {
      const int base = c * 256 + w * 64;   // 640 chunks of 16B
      if (base < 640) {
        const int li = base + l;
        const int nrow = li >> 2, ko2 = (li & 3) * 8;
        const unsigned short* src = Wb + (size_t)(n0 + nrow) * 512 + k0 + ko2;
        __builtin_amdgcn_global_load_lds(
            (const __attribute__((address_space(1))) void*)src,
            (__attribute__((address_space(3))) void*)&Bs[base * 8], 16, 0, 0);
      }
    }
    __syncthreads();

    Frag fa[2], fb[5];
    #pragma unroll
    for (int mi = 0; mi < 2; ++mi)
      fa[mi].u = *(const uint4*)&As[(wm + mi * 16 + (l & 15)) * 32 + (l >> 4) * 8];
    #pragma unroll
    for (int nj = 0; nj < 5; ++nj)
      fb[nj].u = *(const uint4*)&Bs[(wn + nj * 16 + (l & 15)) * 32 + (l >> 4) * 8];
    #pragma unroll
    for (int mi = 0; mi < 2; ++mi)
      #pragma unroll
      for (int nj = 0; nj < 5; ++nj)
        acc[mi][nj] = __builtin_amdgcn_mfma_f32_16x16x32_bf16(fa[mi].v, fb[nj].v, acc[mi][nj], 0, 0, 0);
    __syncthreads();
  }

  #pragma unroll
  for (int mi = 0; mi < 2; ++mi)
    #pragma unroll
    for (int nj = 0; nj < 5; ++nj) {
      const int col = n0 + wn + nj * 16 + (l & 15);
      if (col < 280) {
        #pragma unroll
        for (int r = 0; r < 4; ++r) {
          const int row = mh * 64 + wm + mi * 16 + (l >> 4) * 4 + r;
          if (row < NV_)
            out[((size_t)b * NV_ + row) * 280 + col] = acc[mi][nj][r];
        }
      }
    }
}

// ---------------------------------------------------------------------------
extern "C" void kernel_launch(void* const* d_in, const int* in_sizes, int n_in,
                              void* d_out, int out_size, void* d_ws, size_t ws_size,
                              hipStream_t stream)
{
  const float* v   = (const float*)d_in[0];
  const float* q   = (const float*)d_in[1];
  const float* a   = (const float*)d_in[2];
  const float* Wv  = (const float*)d_in[3];
  const float* bv  = (const float*)d_in[4];
  const float* Wq  = (const float*)d_in[5];
  const float* bq  = (const float*)d_in[6];
  const float* Wa  = (const float*)d_in[7];
  const float* ba  = (const float*)d_in[8];
  const float* Wvr = (const float*)d_in[9];
  const float* bvr = (const float*)d_in[10];
  const float* Wqr = (const float*)d_in[11];
  const float* bqr = (const float*)d_in[12];
  const float* War = (const float*)d_in[13];
  const float* bar = (const float*)d_in[14];
  const float* T   = (const float*)d_in[15];

  unsigned short* wsu = (unsigned short*)d_ws;
  float* wsf = (float*)d_ws;

  // region A (ushort): WmatT [0 .. 20,971,520) — early overlay: bf16 q/a/weights
  unsigned short* WmatT = wsu;
  unsigned short* qb    = wsu;              //  1,835,008 (dead after l1)
  unsigned short* ab    = wsu + 1835008;    //  1,310,720 (dead after l1)
  unsigned short* Wvb   = wsu + 3145728;    //  1,048,576 (dead after l1)
  unsigned short* Wqb   = wsu + 4194304;    //    524,288
  unsigned short* Wab   = wsu + 4718592;    //    524,288
  unsigned short* Wvrb  = wsu + 5242880;    //    262,144 (dead after l2)
  unsigned short* Wqrb  = wsu + 5505024;    //    262,144
  unsigned short* Warb  = wsu + 5767168;    //    262,144  end 6,029,312 < 20.97M ok
  // persistent bf16 intermediates
  unsigned short* vtb   = wsu + 20971520;   //  6,553,600
  unsigned short* qtb   = wsu + 27525120;   //    917,504
  unsigned short* atb   = wsu + 28442624;   //    655,360
  unsigned short* vrb   = wsu + 29097984;   //  6,553,600  end 35,651,584 ush
  // fp32 region
  float* q_r  = wsf + 17825792;             //    917,504 f
  float* a_r  = wsf + 18743296;             //    655,360 f
  float* Tsum = wsf + 19398656;             //      8,192 f   (end 77.6 MB)

  cvt_kernel<<<2944, 256, 0, stream>>>(q, a, Wv, Wq, Wa, Wvr, Wqr, War, wsu);

  l1_gemm<<<992, 256, 0, stream>>>(v, qb, ab, Wvb, Wqb, Wab, bv, bq, ba,
                                   vtb, qtb, atb);
  l2_gemm<<<992, 256, 0, stream>>>(vtb, qtb, atb, Wvrb, Wqrb, Warb,
                                   bvr, bqr, bar, vrb, q_r, a_r);

  tsum_kernel<<<32, 256, 0, stream>>>(T, Tsum);
  build_w_kernel<<<dim3(32, 128), 256, 0, stream>>>(q_r, a_r, Tsum, WmatT);
  final_mfma<<<dim3(4, 128), 256, 0, stream>>>(vrb, WmatT, (float*)d_out);
}